// Round 8
// baseline (220.368 us; speedup 1.0000x reference)
//
#include <hip/hip_runtime.h>
#include <hip/hip_cooperative_groups.h>

namespace cg = cooperative_groups;

#define NINV 0xFFFFFFFFu
static constexpr int D = 64, H = 64, W = 64;
static constexpr int NVOX = D * H * W;      // 262144
static constexpr int NTOT = 2 * NVOX;

// ---------- global union-find (min-index linking, path halving) ----------

__device__ __forceinline__ unsigned find_c(unsigned* P, unsigned i) {
    unsigned p = P[i];
    while (p != i) {
        unsigned gp = P[p];
        if (gp == p) return p;
        P[i] = gp;          // path halving (benign: gp is an ancestor of i)
        i = gp;
        p = P[i];
    }
    return i;
}

__device__ void unite(unsigned* P, unsigned a, unsigned b) {
    for (;;) {
        a = find_c(P, a);
        b = find_c(P, b);
        if (a == b) return;
        if (a > b) { unsigned t = a; a = b; b = t; }
        unsigned old = atomicCAS(&P[b], b, a);
        if (old == b || old == a) return;
        b = old;
    }
}

// ---------- topology: packed-27-bit masks, bit k = dz*9+dy*3+dx ----------
// A18: L1(pair diff) <= 2 (incl. single-axis +-2).  A26: Linf(diff) <= 1.

static constexpr unsigned ALL27 = 0x7FFFFFFu;
static constexpr unsigned XL2 = 0x36DB6DBu, XG0 = 0x6DB6DB6u;
static constexpr unsigned YL2 = 0x0FC7E3Fu, YG0 = 0x7E3F1F8u;
static constexpr unsigned ZL2 = 0x003FFFFu, ZG0 = 0x7FFFE00u;
static constexpr unsigned X0 = 0x1249249u, X2 = 0x4924924u;
static constexpr unsigned Y0 = 0x01C0E07u, Y2 = 0x70381C0u;
static constexpr unsigned Z0 = 0x00001FFu, Z2 = 0x7FC0000u;

__device__ __forceinline__ unsigned dilX(unsigned m) { return m | ((m & XL2) << 1) | ((m & XG0) >> 1); }
__device__ __forceinline__ unsigned dilY(unsigned m) { return m | ((m & YL2) << 3) | ((m & YG0) >> 3); }
__device__ __forceinline__ unsigned dilZ(unsigned m) { return m | ((m & ZL2) << 9) | ((m & ZG0) >> 9); }
__device__ __forceinline__ unsigned dil2(unsigned m) {
    return ((m & X0) << 2) | ((m & X2) >> 2)
         | ((m & Y0) << 6) | ((m & Y2) >> 6)
         | ((m & Z0) << 18) | ((m & Z2) >> 18);
}

__device__ __forceinline__ bool multi18(unsigned mask) {   // #components != 1
    if (mask == 0) return true;
    unsigned comp = mask & (0u - mask);
    for (;;) {
        unsigned a = dilX(comp), b = dilY(comp);
        unsigned n = (dilY(a) | dilZ(a) | dilZ(b) | dil2(comp)) & mask;
        if (n == comp) break;
        comp = n;
    }
    return comp != mask;
}

__device__ __forceinline__ bool multi26(unsigned mask) {
    if (mask == 0) return true;
    unsigned comp = mask & (0u - mask);
    for (;;) {
        unsigned n = dilZ(dilY(dilX(comp))) & mask;
        if (n == comp) break;
        comp = n;
    }
    return comp != mask;
}

__device__ __forceinline__ float weight_lds(const unsigned* __restrict__ h,
                                            int lx, int ly, int lz) {
    int ctr = (lz + 1) * 100 + (ly + 1) * 10 + (lx + 1);
    unsigned c = h[ctr];
    if (c == NINV) return 1.0f;          // background center: simple
    unsigned same = 0;
    int k = 0;
    #pragma unroll
    for (int dz = 0; dz <= 2; ++dz) {
        #pragma unroll
        for (int dy = 0; dy <= 2; ++dy) {
            int base = (lz + dz) * 100 + (ly + dy) * 10 + lx;
            #pragma unroll
            for (int dx = 0; dx <= 2; ++dx) {
                same |= (h[base + dx] == c ? 1u : 0u) << k;
                ++k;
            }
        }
    }
    unsigned m1 = (~same) & ALL27;       // label != center (incl. bg), 18-adj
    unsigned m2 = same & ~(1u << 13);    // same comp minus center, 26-adj
    return (multi18(m1) || multi26(m2)) ? 10.0f : 1.0f;
}

// ---------- merge-phase geometry ----------

static constexpr int FACES_PER_DIR = 7 * 8 * 8;         // 448
static constexpr int FACES_PER_VOL = 3 * FACES_PER_DIR; // 1344
static constexpr int FACES_TOT     = 2 * FACES_PER_VOL; // 2688

// ---------- the single fused cooperative kernel ----------

__global__ __launch_bounds__(512, 4) void fused_k(const float* __restrict__ pred,
                                                  const float* __restrict__ target,
                                                  unsigned* __restrict__ parent,
                                                  float* __restrict__ out) {
    cg::grid_group grid = cg::this_grid();
    __shared__ unsigned sh[2000];        // A: lab0=sh, lab1=sh+512 | C: hP=sh, hT=sh+1000
    __shared__ float sred[8];

    int tb = blockIdx.x;                 // 512 tiles
    int l  = threadIdx.x;
    int tx = (tb & 7) << 3;
    int ty = ((tb >> 3) & 7) << 3;
    int tz = (tb >> 6) << 3;
    int lx = l & 7, ly = (l >> 3) & 7, lz = l >> 6;
    int g = ((tz + lz) << 12) + ((ty + ly) << 6) + (tx + lx);

    // ===== phase A: local CCL for both volumes concurrently =====
    unsigned* lab0 = sh;
    unsigned* lab1 = sh + 512;
    bool fg0 = pred[g]   > 0.5f;
    bool fg1 = target[g] > 0.5f;
    lab0[l] = fg0 ? (unsigned)l : NINV;
    lab1[l] = fg1 ? (unsigned)l : NINV;
    __syncthreads();

    for (;;) {
        int ch = 0;
        if (fg0) {
            unsigned cur = lab0[l], m = cur;
            if (lx > 0) m = min(m, lab0[l - 1]);
            if (lx < 7) m = min(m, lab0[l + 1]);
            if (ly > 0) m = min(m, lab0[l - 8]);
            if (ly < 7) m = min(m, lab0[l + 8]);
            if (lz > 0) m = min(m, lab0[l - 64]);
            if (lz < 7) m = min(m, lab0[l + 64]);
            for (;;) { unsigned p = lab0[m]; if (p >= m) break; m = p; }
            if (m < cur) { lab0[l] = m; ch = 1; }
        }
        if (fg1) {
            unsigned cur = lab1[l], m = cur;
            if (lx > 0) m = min(m, lab1[l - 1]);
            if (lx < 7) m = min(m, lab1[l + 1]);
            if (ly > 0) m = min(m, lab1[l - 8]);
            if (ly < 7) m = min(m, lab1[l + 8]);
            if (lz > 0) m = min(m, lab1[l - 64]);
            if (lz < 7) m = min(m, lab1[l + 64]);
            for (;;) { unsigned p = lab1[m]; if (p >= m) break; m = p; }
            if (m < cur) { lab1[l] = m; ch = 1; }
        }
        if (__syncthreads_count(ch) == 0) break;
    }

    unsigned r0 = NINV, r1 = NINV;
    if (fg0) {
        unsigned rr = lab0[l];
        r0 = (unsigned)(((tz + (int)(rr >> 6)) << 12)
                      + ((ty + (int)((rr >> 3) & 7)) << 6)
                      +  (tx + (int)(rr & 7)));
    }
    if (fg1) {
        unsigned rr = lab1[l];
        r1 = (unsigned)NVOX
           + (unsigned)(((tz + (int)(rr >> 6)) << 12)
                      + ((ty + (int)((rr >> 3) & 7)) << 6)
                      +  (tx + (int)(rr & 7)));
    }
    parent[g] = r0;
    parent[NVOX + g] = r1;
    if (tb == 0 && l == 0) atomicExch(out, 0.0f);   // zero the poisoned output

    grid.sync();

    // ===== phase B: face merges (waves 0..2687 of 4096) =====
    {
        int wave = tb * 8 + (l >> 6);
        int lane = l & 63;
        if (wave < FACES_TOT) {
            int vol = wave / FACES_PER_VOL;
            int f   = wave - vol * FACES_PER_VOL;
            int dir = f / FACES_PER_DIR;
            int ff  = f - dir * FACES_PER_DIR;
            int plane = ff >> 6;
            int tf    = ff & 63;
            int a0 = ((tf & 7) << 3) + (lane & 7);
            int a1 = ((tf >> 3) << 3) + (lane >> 3);
            int x, y, z, stride;
            if (dir == 0)      { x = plane * 8 + 7; y = a0; z = a1; stride = 1; }
            else if (dir == 1) { y = plane * 8 + 7; x = a0; z = a1; stride = 64; }
            else               { z = plane * 8 + 7; x = a0; y = a1; stride = 4096; }
            int i = vol * NVOX + (z << 12) + (y << 6) + x;

            unsigned ra = parent[i];
            unsigned rb = parent[i + stride];
            bool valid = (ra != NINV) && (rb != NINV);
            unsigned long long key = valid ? (((unsigned long long)ra << 32) | rb) : ~0ull;

            bool leader = valid;
            #pragma unroll 8
            for (int j = 0; j < 64; ++j) {
                unsigned long long kj = __shfl(key, j, 64);
                if (j < lane && kj == key) leader = false;
            }
            if (leader) unite(parent, ra, rb);
        }
    }

    grid.sync();

    // ===== phase C: halo chase-load + topology + weighted BCE + reduce =====
    unsigned* hP = sh;
    unsigned* hT = sh + 1000;
    for (int e = l; e < 1000; e += 512) {
        int hx = e % 10, hy = (e / 10) % 10, hz = e / 100;
        int gx = min(max(tx + hx - 1, 0), 63);
        int gy = min(max(ty + hy - 1, 0), 63);
        int gz = min(max(tz + hz - 1, 0), 63);
        int gg = (gz << 12) + (gy << 6) + gx;
        unsigned p = parent[gg];
        if (p != NINV) { unsigned q; while ((q = parent[p]) != p) p = q; }
        hP[e] = p;
        unsigned s = parent[NVOX + gg];
        if (s != NINV) { unsigned q; while ((q = parent[s]) != s) s = q; }
        hT[e] = s;
    }
    __syncthreads();

    float wP = weight_lds(hP, lx, ly, lz);
    float wT = weight_lds(hT, lx, ly, lz);
    float wp = wP * pred[g];
    float wl = wT * target[g];
    float l1pe = log1pf(expf(-fabsf(wp)));
    float sp_pos = fmaxf(wp, 0.0f) + l1pe;
    float sp_neg = fmaxf(-wp, 0.0f) + l1pe;
    float err = wl * sp_neg + (1.0f - wl) * sp_pos;

    #pragma unroll
    for (int o = 32; o > 0; o >>= 1) err += __shfl_down(err, o, 64);
    int lane = l & 63;
    int wv = l >> 6;
    if (lane == 0) sred[wv] = err;
    __syncthreads();
    if (l == 0) {
        float s = 0.0f;
        #pragma unroll
        for (int w = 0; w < 8; ++w) s += sred[w];
        atomicAdd(out, s);
    }
}

// ---------------- launch ----------------

extern "C" void kernel_launch(void* const* d_in, const int* in_sizes, int n_in,
                              void* d_out, int out_size, void* d_ws, size_t ws_size,
                              hipStream_t stream) {
    const float* pred   = (const float*)d_in[0];
    const float* target = (const float*)d_in[1];
    float* out = (float*)d_out;
    unsigned* parent = (unsigned*)d_ws;          // [2*NVOX]

    void* args[] = { (void*)&pred, (void*)&target, (void*)&parent, (void*)&out };
    hipLaunchCooperativeKernel((const void*)fused_k, dim3(512), dim3(512),
                               args, 0, stream);
}

// Round 9
// 109.549 us; speedup vs baseline: 2.0116x; 2.0116x over previous
//
#include <hip/hip_runtime.h>

#define NINV 0xFFFFFFFFu
static constexpr int D = 64, H = 64, W = 64;
static constexpr int NVOX = D * H * W;      // 262144
static constexpr int NTOT = 2 * NVOX;       // both volumes, contiguous in ws

// ---------- global union-find primitives (min-index linking, path halving) ----------

__device__ __forceinline__ unsigned find_c(unsigned* P, unsigned i) {
    unsigned p = P[i];
    while (p != i) {
        unsigned gp = P[p];
        if (gp == p) return p;
        P[i] = gp;          // path halving (benign: gp is an ancestor of i)
        i = gp;
        p = P[i];
    }
    return i;
}

__device__ void unite(unsigned* P, unsigned a, unsigned b) {
    for (;;) {
        a = find_c(P, a);
        b = find_c(P, b);
        if (a == b) return;
        if (a > b) { unsigned t = a; a = b; b = t; }
        unsigned old = atomicCAS(&P[b], b, a);
        if (old == b || old == a) return;
        b = old;
    }
}

// ---------- phase 1a: local CCL per 8x8x8 tile in LDS ----------
// (single volume per block: LDS accesses are lane-contiguous -> conflict-free,
//  unlike the fused dual-array variant which showed 370K bank conflicts)

__global__ __launch_bounds__(512) void local_ccl_k(const float* __restrict__ pred,
                                                   const float* __restrict__ target,
                                                   unsigned* __restrict__ parent,
                                                   float* __restrict__ out) {
    __shared__ unsigned lab[512];
    int tb  = blockIdx.x & 511;
    int vol = blockIdx.x >> 9;
    const float* src = vol ? target : pred;
    int tx = (tb & 7) << 3;
    int ty = ((tb >> 3) & 7) << 3;
    int tz = (tb >> 6) << 3;

    int l = threadIdx.x;
    int lx = l & 7, ly = (l >> 3) & 7, lz = l >> 6;
    int g = ((tz + lz) << 12) + ((ty + ly) << 6) + (tx + lx);

    if (blockIdx.x == 0 && l == 0) *out = 0.0f;   // replaces the memset node

    bool fg = src[g] > 0.5f;
    lab[l] = fg ? (unsigned)l : NINV;
    __syncthreads();

    for (;;) {
        int my_changed = 0;
        if (fg) {
            unsigned cur = lab[l];
            unsigned m = cur;
            if (lx > 0) m = min(m, lab[l - 1]);
            if (lx < 7) m = min(m, lab[l + 1]);
            if (ly > 0) m = min(m, lab[l - 8]);
            if (ly < 7) m = min(m, lab[l + 8]);
            if (lz > 0) m = min(m, lab[l - 64]);
            if (lz < 7) m = min(m, lab[l + 64]);
            for (;;) { unsigned p = lab[m]; if (p >= m) break; m = p; }  // chase
            if (m < cur) { lab[l] = m; my_changed = 1; }
        }
        if (__syncthreads_count(my_changed) == 0) break;
    }

    unsigned r = NINV;
    if (fg) {
        unsigned rr = lab[l];
        r = (unsigned)(vol * NVOX)
          + (unsigned)(((tz + (int)(rr >> 6)) << 12)
                     + ((ty + (int)((rr >> 3) & 7)) << 6)
                     +  (tx + (int)(rr & 7)));
    }
    parent[vol * NVOX + g] = r;
}

// ---------- phase 1b: merge across tile faces, one wave per 8x8 tile-face ----------

static constexpr int FACES_PER_DIR = 7 * 8 * 8;         // 448
static constexpr int FACES_PER_VOL = 3 * FACES_PER_DIR; // 1344
static constexpr int FACES_TOT     = 2 * FACES_PER_VOL; // 2688

__global__ void merge_k(unsigned* __restrict__ parent) {
    int wave = (int)((blockIdx.x * blockDim.x + threadIdx.x) >> 6);
    int lane = threadIdx.x & 63;
    if (wave >= FACES_TOT) return;
    int vol = wave / FACES_PER_VOL;
    int f   = wave - vol * FACES_PER_VOL;
    int dir = f / FACES_PER_DIR;
    int ff  = f - dir * FACES_PER_DIR;
    int plane = ff >> 6;
    int tf    = ff & 63;
    int a0 = ((tf & 7) << 3) + (lane & 7);
    int a1 = ((tf >> 3) << 3) + (lane >> 3);
    int x, y, z, stride;
    if (dir == 0)      { x = plane * 8 + 7; y = a0; z = a1; stride = 1; }
    else if (dir == 1) { y = plane * 8 + 7; x = a0; z = a1; stride = 64; }
    else               { z = plane * 8 + 7; x = a0; y = a1; stride = 4096; }
    int i = vol * NVOX + (z << 12) + (y << 6) + x;

    unsigned ra = parent[i];
    unsigned rb = parent[i + stride];
    bool valid = (ra != NINV) && (rb != NINV);
    unsigned long long key = valid ? (((unsigned long long)ra << 32) | rb) : ~0ull;

    bool leader = valid;
    #pragma unroll 8
    for (int j = 0; j < 64; ++j) {
        unsigned long long kj = __shfl(key, j, 64);
        if (j < lane && kj == key) leader = false;
    }
    if (leader) unite(parent, ra, rb);
}

// ---------- phase 2: halo-chase + packed-27-bit topology + weighted BCE ----------
// Bit k = dz*9 + dy*3 + dx (dz,dy,dx in 0..2); center = bit 13.
// Reference adjacency is over PAIRS of the 27 positions: diffs range [-2,2].
// A18: L1(diff) <= 2 (incl. single-axis +-2).  A26: Linf(diff) <= 1.

static constexpr unsigned ALL27 = 0x7FFFFFFu;
static constexpr unsigned XL2 = 0x36DB6DBu, XG0 = 0x6DB6DB6u;
static constexpr unsigned YL2 = 0x0FC7E3Fu, YG0 = 0x7E3F1F8u;
static constexpr unsigned ZL2 = 0x003FFFFu, ZG0 = 0x7FFFE00u;
static constexpr unsigned X0 = 0x1249249u, X2 = 0x4924924u;
static constexpr unsigned Y0 = 0x01C0E07u, Y2 = 0x70381C0u;
static constexpr unsigned Z0 = 0x00001FFu, Z2 = 0x7FC0000u;

__device__ __forceinline__ unsigned dilX(unsigned m) { return m | ((m & XL2) << 1) | ((m & XG0) >> 1); }
__device__ __forceinline__ unsigned dilY(unsigned m) { return m | ((m & YL2) << 3) | ((m & YG0) >> 3); }
__device__ __forceinline__ unsigned dilZ(unsigned m) { return m | ((m & ZL2) << 9) | ((m & ZG0) >> 9); }
__device__ __forceinline__ unsigned dil2(unsigned m) {
    return ((m & X0) << 2) | ((m & X2) >> 2)
         | ((m & Y0) << 6) | ((m & Y2) >> 6)
         | ((m & Z0) << 18) | ((m & Z2) >> 18);
}

__device__ __forceinline__ bool multi18(unsigned mask) {   // #components != 1
    if (mask == 0) return true;
    unsigned comp = mask & (0u - mask);
    for (;;) {
        unsigned a = dilX(comp), b = dilY(comp);
        unsigned n = (dilY(a) | dilZ(a) | dilZ(b) | dil2(comp)) & mask;
        if (n == comp) break;
        comp = n;
    }
    return comp != mask;
}

__device__ __forceinline__ bool multi26(unsigned mask) {
    if (mask == 0) return true;
    unsigned comp = mask & (0u - mask);
    for (;;) {
        unsigned n = dilZ(dilY(dilX(comp))) & mask;
        if (n == comp) break;
        comp = n;
    }
    return comp != mask;
}

__device__ __forceinline__ float weight_lds(const unsigned* __restrict__ h,
                                            int lx, int ly, int lz) {
    int ctr = (lz + 1) * 100 + (ly + 1) * 10 + (lx + 1);
    unsigned c = h[ctr];
    if (c == NINV) return 1.0f;          // background center: simple
    unsigned same = 0;
    int k = 0;
    #pragma unroll
    for (int dz = 0; dz <= 2; ++dz) {
        #pragma unroll
        for (int dy = 0; dy <= 2; ++dy) {
            int base = (lz + dz) * 100 + (ly + dy) * 10 + lx;
            #pragma unroll
            for (int dx = 0; dx <= 2; ++dx) {
                same |= (h[base + dx] == c ? 1u : 0u) << k;
                ++k;
            }
        }
    }
    unsigned m1 = (~same) & ALL27;       // label != center (incl. bg), 18-adj
    unsigned m2 = same & ~(1u << 13);    // same comp minus center, 26-adj
    return (multi18(m1) || multi26(m2)) ? 10.0f : 1.0f;
}

__global__ __launch_bounds__(512) void final_k(const float* __restrict__ pred,
                                               const float* __restrict__ target,
                                               unsigned* __restrict__ parent,
                                               float* __restrict__ out) {
    __shared__ unsigned hP[1000], hT[1000];
    __shared__ float sred[8];

    int l = threadIdx.x;
    int tb = blockIdx.x;                 // 512 tiles
    int tx = (tb & 7) << 3;
    int ty = ((tb >> 3) & 7) << 3;
    int tz = (tb >> 6) << 3;

    for (int e = l; e < 1000; e += 512) {
        int hx = e % 10, hy = (e / 10) % 10, hz = e / 100;
        int gx = min(max(tx + hx - 1, 0), 63);
        int gy = min(max(ty + hy - 1, 0), 63);
        int gz = min(max(tz + hz - 1, 0), 63);
        int g = (gz << 12) + (gy << 6) + gx;
        // chase to root (forest is quiescent; chains are short post-merge)
        unsigned p = parent[g];
        if (p != NINV) { unsigned q; while ((q = parent[p]) != p) p = q; }
        hP[e] = p;
        unsigned s = parent[NVOX + g];
        if (s != NINV) { unsigned q; while ((q = parent[s]) != s) s = q; }
        hT[e] = s;
    }
    __syncthreads();

    int lx = l & 7, ly = (l >> 3) & 7, lz = l >> 6;
    int g = ((tz + lz) << 12) + ((ty + ly) << 6) + (tx + lx);

    float wP = weight_lds(hP, lx, ly, lz);
    float wT = weight_lds(hT, lx, ly, lz);
    float wp = wP * pred[g];
    float wl = wT * target[g];
    float l1pe = log1pf(expf(-fabsf(wp)));
    float sp_pos = fmaxf(wp, 0.0f) + l1pe;
    float sp_neg = fmaxf(-wp, 0.0f) + l1pe;
    float err = wl * sp_neg + (1.0f - wl) * sp_pos;

    #pragma unroll
    for (int o = 32; o > 0; o >>= 1) err += __shfl_down(err, o, 64);
    int lane = l & 63;
    int wv = l >> 6;
    if (lane == 0) sred[wv] = err;
    __syncthreads();
    if (l == 0) {
        float s = 0.0f;
        #pragma unroll
        for (int w = 0; w < 8; ++w) s += sred[w];
        atomicAdd(out, s);
    }
}

// ---------------- launch ----------------

extern "C" void kernel_launch(void* const* d_in, const int* in_sizes, int n_in,
                              void* d_out, int out_size, void* d_ws, size_t ws_size,
                              hipStream_t stream) {
    const float* pred   = (const float*)d_in[0];
    const float* target = (const float*)d_in[1];
    float* out = (float*)d_out;
    unsigned* parent = (unsigned*)d_ws;          // [2*NVOX]

    local_ccl_k<<<1024, 512, 0, stream>>>(pred, target, parent, out);
    merge_k<<<FACES_TOT * 64 / 256, 256, 0, stream>>>(parent);
    final_k<<<512, 512, 0, stream>>>(pred, target, parent, out);
}